// Round 7
// baseline (2153.879 us; speedup 1.0000x reference)
//
#include <hip/hip_runtime.h>

#define N_NODES 100000
#define N_EDGES 3200000
#define N_GRAPHS 512
#define F_IN 128
#define F_HID 64
#define F_CAT 192
#define F_OUT 10

#define N_CHUNKS 4
#define CHUNK_DIV 25000             // nodes per source-chunk; hp slice = 3.2 MB < 4 MB XCD L2
#define N_CNT (N_NODES * N_CHUNKS)  // 400000 counters

#define AGG_BLOCKS 1024             // 4 blocks/CU on 256 CUs -> co-resident
#define WAVES_TOTAL (AGG_BLOCKS * 4)
#define NODES_PER_WAVE 25           // ceil(100000 / 4096)
#define MAX_SPIN 3000               // bounded spin: perf-only barrier, no deadlock

typedef unsigned short ushort_t;
typedef unsigned int uint_t;

static __device__ __forceinline__ ushort_t f2bf(float f) {
    uint_t u = __float_as_uint(f);
    u = (u + 0x7FFFu + ((u >> 16) & 1u)) >> 16;  // round-to-nearest-even
    return (ushort_t)u;
}
static __device__ __forceinline__ float bf2f(ushort_t h) {
    return __uint_as_float((uint_t)h << 16);
}

// soft grid barrier: each block bumps ctr once, thread0 spins (bounded) until
// all AGG_BLOCKS arrived. Performance-only: timeout proceeds safely.
static __device__ __forceinline__ void soft_barrier(int* ctr) {
    __syncthreads();
    if (threadIdx.x == 0) {
        atomicAdd(ctr, 1);
        volatile int* vc = ctr;
        int spins = 0;
        while (*vc < AGG_BLOCKS && spins < MAX_SPIN) {
            __builtin_amdgcn_s_sleep(4);
            ++spins;
        }
    }
    __syncthreads();
}

// ------------------------------------------- per-(dest,src-chunk) histogram ----
__global__ void deg2_kernel(const int* __restrict__ row, const int* __restrict__ col,
                            int* __restrict__ cnt2) {
    int e = blockIdx.x * blockDim.x + threadIdx.x;
    if (e < N_EDGES) {
        int ch = row[e] / CHUNK_DIV;
        atomicAdd(&cnt2[col[e] * N_CHUNKS + ch], 1);
    }
}

__global__ void dinv_kernel(const int* __restrict__ cnt2, float* __restrict__ dinv) {
    int i = blockIdx.x * blockDim.x + threadIdx.x;
    if (i < N_NODES) {
        int d = cnt2[i * 4] + cnt2[i * 4 + 1] + cnt2[i * 4 + 2] + cnt2[i * 4 + 3];
        dinv[i] = d > 0 ? rsqrtf((float)d) : 0.0f;
    }
}

// ------------------------------------------------- two-level prefix scan ----
__global__ void scan1_kernel(const int* __restrict__ cnt, int* __restrict__ start,
                             int* __restrict__ bsum) {
    __shared__ int s[1024];
    int t = threadIdx.x;  // 1024
    int i = blockIdx.x * 1024 + t;
    int v = (i < N_CNT) ? cnt[i] : 0;
    s[t] = v;
    __syncthreads();
    for (int o = 1; o < 1024; o <<= 1) {
        int x = (t >= o) ? s[t - o] : 0;
        __syncthreads();
        s[t] += x;
        __syncthreads();
    }
    if (i < N_CNT) start[i] = s[t] - v;
    if (t == 1023) bsum[blockIdx.x] = s[1023];
}

__global__ void scan2_kernel(int* __restrict__ bsum, int nblk) {
    __shared__ int s[512];
    int t = threadIdx.x;  // 512
    int v = (t < nblk) ? bsum[t] : 0;
    s[t] = v;
    __syncthreads();
    for (int o = 1; o < 512; o <<= 1) {
        int x = (t >= o) ? s[t - o] : 0;
        __syncthreads();
        s[t] += x;
        __syncthreads();
    }
    if (t < nblk) bsum[t] = s[t] - v;
}

__global__ void scan3_kernel(int* __restrict__ start, const int* __restrict__ bsum) {
    int i = blockIdx.x * blockDim.x + threadIdx.x;
    if (i < N_CNT) start[i] += bsum[i >> 10];
    if (i == 0) start[N_CNT] = N_EDGES;
}

// ------------------------------------------------------- CSC placement -----
__global__ void place_kernel(const int* __restrict__ row, const int* __restrict__ col,
                             const int* __restrict__ start2, int* __restrict__ cursor2,
                             int* __restrict__ csr_row) {
    int e = blockIdx.x * blockDim.x + threadIdx.x;
    if (e < N_EDGES) {
        int r = row[e];
        int d = col[e];
        int slot = d * N_CHUNKS + r / CHUNK_DIV;
        int ofs = atomicAdd(&cursor2[slot], 1);
        csr_row[start2[slot] + ofs] = r;
    }
}

// ------------------------------------------------------------------ GEMM ----
template <int K>
__global__ void gemm_kernel(const float* __restrict__ X, const float* __restrict__ W,
                            const float* __restrict__ dinv, ushort_t* __restrict__ HP) {
    __shared__ float Ws[K][64];
    __shared__ float Xs[16][K];
    int tid = threadIdx.x;  // 256
    for (int i = tid; i < K * 64; i += 256) Ws[i / 64][i % 64] = W[i];
    int row0 = blockIdx.x * 16;
    for (int i = tid; i < 16 * K; i += 256) {
        int r = i / K, k = i % K;
        int gr = row0 + r;
        Xs[r][k] = (gr < N_NODES) ? X[(size_t)gr * K + k] : 0.0f;
    }
    __syncthreads();
    int c = tid & 63;
    int rs = tid >> 6;
    for (int r = rs; r < 16; r += 4) {
        float acc = 0.0f;
#pragma unroll
        for (int k = 0; k < K; ++k) acc += Xs[r][k] * Ws[k][c];
        int gr = row0 + r;
        if (gr < N_NODES) HP[(size_t)gr * 64 + c] = f2bf(acc * dinv[gr]);
    }
}

// ------------------------------------------------------------- aggregate ----
// Persistent co-resident grid. Each wave owns NODES_PER_WAVE nodes (acc in
// regs, statically indexed). Phase ph: all waves gather ONLY from hp slice ph
// (3.2 MB, L2-resident). Soft grid barrier keeps phases coherent chip-wide.
template <bool WRITE, bool COUNT, int POFF>
__global__ __launch_bounds__(256, 4) void aggregate_kernel(
    const int* __restrict__ csr_row, const int* __restrict__ start2,
    const ushort_t* __restrict__ hp, const float* __restrict__ dinv,
    const float* __restrict__ b, float* __restrict__ out,
    const int* __restrict__ batch, float* __restrict__ pooled,
    float* __restrict__ cntg, int* __restrict__ bar) {
    int wave = blockIdx.x * 4 + (threadIdx.x >> 6);
    int c = threadIdx.x & 63;
    float acc[NODES_PER_WAVE];
#pragma unroll
    for (int i = 0; i < NODES_PER_WAVE; ++i) acc[i] = 0.0f;

    for (int ph = 0; ph < N_CHUNKS; ++ph) {
#pragma unroll
        for (int i = 0; i < NODES_PER_WAVE; ++i) {
            int node = wave + i * WAVES_TOTAL;
            if (node < N_NODES) {
                int s0 = start2[node * N_CHUNKS + ph];
                int s1 = start2[node * N_CHUNKS + ph + 1];
                float a = acc[i];
                int j = s0;
                for (; j + 7 < s1; j += 8) {
                    int r0 = csr_row[j + 0];
                    int r1 = csr_row[j + 1];
                    int r2 = csr_row[j + 2];
                    int r3 = csr_row[j + 3];
                    int r4 = csr_row[j + 4];
                    int r5 = csr_row[j + 5];
                    int r6 = csr_row[j + 6];
                    int r7 = csr_row[j + 7];
                    float v0 = bf2f(hp[r0 * 64 + c]);
                    float v1 = bf2f(hp[r1 * 64 + c]);
                    float v2 = bf2f(hp[r2 * 64 + c]);
                    float v3 = bf2f(hp[r3 * 64 + c]);
                    float v4 = bf2f(hp[r4 * 64 + c]);
                    float v5 = bf2f(hp[r5 * 64 + c]);
                    float v6 = bf2f(hp[r6 * 64 + c]);
                    float v7 = bf2f(hp[r7 * 64 + c]);
                    a += ((v0 + v1) + (v2 + v3)) + ((v4 + v5) + (v6 + v7));
                }
                for (; j < s1; ++j) a += bf2f(hp[csr_row[j] * 64 + c]);
                acc[i] = a;
            }
        }
        if (ph < N_CHUNKS - 1) soft_barrier(&bar[ph]);
    }

    // epilogue: bias + relu + store + fused mean-pool accumulation
#pragma unroll
    for (int i = 0; i < NODES_PER_WAVE; ++i) {
        int node = wave + i * WAVES_TOTAL;
        if (node < N_NODES) {
            float v = fmaxf(dinv[node] * acc[i] + b[c], 0.0f);
            if (WRITE) out[(size_t)node * 64 + c] = v;
            int g = batch[node];
            atomicAdd(&pooled[g * F_CAT + POFF + c], v);
            if (COUNT && c == 0) atomicAdd(&cntg[g], 1.0f);
        }
    }
}

// ------------------------------------------------------------------ head ----
__global__ void head_kernel(const float* __restrict__ pooled, const float* __restrict__ cnt,
                            const float* __restrict__ Wf, const float* __restrict__ bf,
                            float* __restrict__ out) {
    __shared__ float p[F_CAT];
    __shared__ float logits[F_OUT];
    int g = blockIdx.x;
    int tid = threadIdx.x;  // 64
    float invc = 1.0f / fmaxf(cnt[g], 1.0f);
    for (int i = tid; i < F_CAT; i += 64) p[i] = pooled[g * F_CAT + i] * invc;
    __syncthreads();
    if (tid < F_OUT) {
        float acc = bf[tid];
        for (int k = 0; k < F_CAT; ++k) acc += p[k] * Wf[k * F_OUT + tid];
        logits[tid] = acc;
    }
    __syncthreads();
    if (tid == 0) {
        float m = -1e30f;
        for (int j = 0; j < F_OUT; ++j) m = fmaxf(m, logits[j]);
        float s = 0.0f;
        float ex[F_OUT];
        for (int j = 0; j < F_OUT; ++j) { ex[j] = __expf(logits[j] - m); s += ex[j]; }
        float inv = 1.0f / s;
        for (int j = 0; j < F_OUT; ++j) out[g * F_OUT + j] = ex[j] * inv;
    }
}

// ---------------------------------------------------------------- launch ----
extern "C" void kernel_launch(void* const* d_in, const int* in_sizes, int n_in,
                              void* d_out, int out_size, void* d_ws, size_t ws_size,
                              hipStream_t stream) {
    const float* X0 = (const float*)d_in[0];
    const int* ei = (const int*)d_in[1];
    const int* batch = (const int*)d_in[2];
    const float* W1 = (const float*)d_in[3];
    const float* b1 = (const float*)d_in[4];
    const float* W2 = (const float*)d_in[5];
    const float* b2 = (const float*)d_in[6];
    const float* W3 = (const float*)d_in[7];
    const float* b3 = (const float*)d_in[8];
    const float* Wf = (const float*)d_in[9];
    const float* bf = (const float*)d_in[10];
    float* out = (float*)d_out;

    const int* row = ei;
    const int* col = ei + N_EDGES;

    const int SCAN_BLOCKS = (N_CNT + 1023) / 1024;  // 391

    // ---- workspace layout ----
    char* wp = (char*)d_ws;
    int* cnt2 = (int*)wp;       wp += (size_t)N_CNT * 4;
    int* cursor2 = (int*)wp;    wp += (size_t)N_CNT * 4;
    float* pooled = (float*)wp; wp += (size_t)N_GRAPHS * F_CAT * 4;
    float* cntg = (float*)wp;   wp += (size_t)N_GRAPHS * 4;
    int* bars = (int*)wp;       wp += (size_t)12 * 4;  // 3 layers x 3 barriers
    size_t zero_bytes = (size_t)(wp - (char*)d_ws);
    float* dinv = (float*)wp;   wp += (size_t)N_NODES * 4;
    int* start2 = (int*)wp;     wp += (size_t)(N_CNT + 4) * 4;
    int* bsum = (int*)wp;       wp += (size_t)512 * 4;
    int* csr_row = (int*)wp;    wp += (size_t)N_EDGES * 4;
    ushort_t* h = (ushort_t*)wp; wp += (size_t)N_NODES * 64 * 2;
    float* x1 = (float*)wp;     wp += (size_t)N_NODES * 64 * 4;
    float* x2 = (float*)wp;     wp += (size_t)N_NODES * 64 * 4;

    hipMemsetAsync(d_ws, 0, zero_bytes, stream);

    deg2_kernel<<<(N_EDGES + 255) / 256, 256, 0, stream>>>(row, col, cnt2);
    dinv_kernel<<<(N_NODES + 255) / 256, 256, 0, stream>>>(cnt2, dinv);
    scan1_kernel<<<SCAN_BLOCKS, 1024, 0, stream>>>(cnt2, start2, bsum);
    scan2_kernel<<<1, 512, 0, stream>>>(bsum, SCAN_BLOCKS);
    scan3_kernel<<<(N_CNT + 255) / 256, 256, 0, stream>>>(start2, bsum);
    place_kernel<<<(N_EDGES + 255) / 256, 256, 0, stream>>>(row, col, start2, cursor2, csr_row);

    const int gemm_blocks = (N_NODES + 15) / 16;

    // ---- layer 1 ----
    gemm_kernel<128><<<gemm_blocks, 256, 0, stream>>>(X0, W1, dinv, h);
    aggregate_kernel<true, true, 0><<<AGG_BLOCKS, 256, 0, stream>>>(
        csr_row, start2, h, dinv, b1, x1, batch, pooled, cntg, bars + 0);
    // ---- layer 2 ----
    gemm_kernel<64><<<gemm_blocks, 256, 0, stream>>>(x1, W2, dinv, h);
    aggregate_kernel<true, false, 64><<<AGG_BLOCKS, 256, 0, stream>>>(
        csr_row, start2, h, dinv, b2, x2, batch, pooled, cntg, bars + 3);
    // ---- layer 3 ----
    gemm_kernel<64><<<gemm_blocks, 256, 0, stream>>>(x2, W3, dinv, h);
    aggregate_kernel<false, false, 128><<<AGG_BLOCKS, 256, 0, stream>>>(
        csr_row, start2, h, dinv, b3, nullptr, batch, pooled, cntg, bars + 6);
    // ---- head ----
    head_kernel<<<N_GRAPHS, 64, 0, stream>>>(pooled, cntg, Wf, bf, out);
}

// Round 8
// 1399.373 us; speedup vs baseline: 1.5392x; 1.5392x over previous
//
#include <hip/hip_runtime.h>

#define N_NODES 100000
#define N_EDGES 3200000
#define N_GRAPHS 512
#define F_IN 128
#define F_HID 64
#define F_CAT 192
#define F_OUT 10

#define N_CHUNKS 4
#define CHUNK_DIV 25000             // nodes per source-chunk; hp slice = 3.2 MB < 4 MB XCD L2
#define N_CNT (N_NODES * N_CHUNKS)  // 400000 counters

typedef unsigned short ushort_t;
typedef unsigned int uint_t;

static __device__ __forceinline__ ushort_t f2bf(float f) {
    uint_t u = __float_as_uint(f);
    u = (u + 0x7FFFu + ((u >> 16) & 1u)) >> 16;  // round-to-nearest-even
    return (ushort_t)u;
}
static __device__ __forceinline__ float bf2f(ushort_t h) {
    return __uint_as_float((uint_t)h << 16);
}

// ------------------------------------------- per-(dest,src-chunk) histogram ----
__global__ void deg2_kernel(const int* __restrict__ row, const int* __restrict__ col,
                            int* __restrict__ cnt2) {
    int e = blockIdx.x * blockDim.x + threadIdx.x;
    if (e < N_EDGES) {
        int ch = row[e] / CHUNK_DIV;
        atomicAdd(&cnt2[col[e] * N_CHUNKS + ch], 1);
    }
}

__global__ void dinv_kernel(const int* __restrict__ cnt2, float* __restrict__ dinv) {
    int i = blockIdx.x * blockDim.x + threadIdx.x;
    if (i < N_NODES) {
        int d = cnt2[i * 4] + cnt2[i * 4 + 1] + cnt2[i * 4 + 2] + cnt2[i * 4 + 3];
        dinv[i] = d > 0 ? rsqrtf((float)d) : 0.0f;
    }
}

// ------------------------------------------------- two-level prefix scan ----
__global__ void scan1_kernel(const int* __restrict__ cnt, int* __restrict__ start,
                             int* __restrict__ bsum) {
    __shared__ int s[1024];
    int t = threadIdx.x;  // 1024
    int i = blockIdx.x * 1024 + t;
    int v = (i < N_CNT) ? cnt[i] : 0;
    s[t] = v;
    __syncthreads();
    for (int o = 1; o < 1024; o <<= 1) {
        int x = (t >= o) ? s[t - o] : 0;
        __syncthreads();
        s[t] += x;
        __syncthreads();
    }
    if (i < N_CNT) start[i] = s[t] - v;
    if (t == 1023) bsum[blockIdx.x] = s[1023];
}

__global__ void scan2_kernel(int* __restrict__ bsum, int nblk) {
    __shared__ int s[512];
    int t = threadIdx.x;  // 512
    int v = (t < nblk) ? bsum[t] : 0;
    s[t] = v;
    __syncthreads();
    for (int o = 1; o < 512; o <<= 1) {
        int x = (t >= o) ? s[t - o] : 0;
        __syncthreads();
        s[t] += x;
        __syncthreads();
    }
    if (t < nblk) bsum[t] = s[t] - v;
}

__global__ void scan3_kernel(int* __restrict__ start, const int* __restrict__ bsum) {
    int i = blockIdx.x * blockDim.x + threadIdx.x;
    if (i < N_CNT) start[i] += bsum[i >> 10];
    if (i == 0) start[N_CNT] = N_EDGES;
}

// ------------------------------------------------------- CSC placement -----
__global__ void place_kernel(const int* __restrict__ row, const int* __restrict__ col,
                             const int* __restrict__ start2, int* __restrict__ cursor2,
                             int* __restrict__ csr_row) {
    int e = blockIdx.x * blockDim.x + threadIdx.x;
    if (e < N_EDGES) {
        int r = row[e];
        int d = col[e];
        int slot = d * N_CHUNKS + r / CHUNK_DIV;
        int ofs = atomicAdd(&cursor2[slot], 1);
        csr_row[start2[slot] + ofs] = r;
    }
}

// ------------------------------------------------------------------ GEMM ----
template <int K>
__global__ void gemm_kernel(const float* __restrict__ X, const float* __restrict__ W,
                            const float* __restrict__ dinv, ushort_t* __restrict__ HP) {
    __shared__ float Ws[K][64];
    __shared__ float Xs[16][K];
    int tid = threadIdx.x;  // 256
    for (int i = tid; i < K * 64; i += 256) Ws[i / 64][i % 64] = W[i];
    int row0 = blockIdx.x * 16;
    for (int i = tid; i < 16 * K; i += 256) {
        int r = i / K, k = i % K;
        int gr = row0 + r;
        Xs[r][k] = (gr < N_NODES) ? X[(size_t)gr * K + k] : 0.0f;
    }
    __syncthreads();
    int c = tid & 63;
    int rs = tid >> 6;
    for (int r = rs; r < 16; r += 4) {
        float acc = 0.0f;
#pragma unroll
        for (int k = 0; k < K; ++k) acc += Xs[r][k] * Ws[k][c];
        int gr = row0 + r;
        if (gr < N_NODES) HP[(size_t)gr * 64 + c] = f2bf(acc * dinv[gr]);
    }
}

// -------------------------------------------------------- phased aggregate ----
// Per phase ph: one wave per node, gather only from hp slice ph (3.2 MB,
// L2-resident since the whole dispatch touches only that slice).
// partial[node][c] accumulates across the 4 phase dispatches.
__global__ void agg_phase_kernel(const int* __restrict__ csr_row, const int* __restrict__ start2,
                                 const ushort_t* __restrict__ hp, float* __restrict__ partial,
                                 int ph, int first) {
    int node = blockIdx.x * 4 + (threadIdx.x >> 6);  // exact: 100000 = 4*25000
    int c = threadIdx.x & 63;
    int s0 = start2[node * N_CHUNKS + ph];
    int s1 = start2[node * N_CHUNKS + ph + 1];
    float a = first ? 0.0f : partial[(size_t)node * 64 + c];
    int j = s0;
    for (; j + 7 < s1; j += 8) {
        int r0 = csr_row[j + 0];
        int r1 = csr_row[j + 1];
        int r2 = csr_row[j + 2];
        int r3 = csr_row[j + 3];
        int r4 = csr_row[j + 4];
        int r5 = csr_row[j + 5];
        int r6 = csr_row[j + 6];
        int r7 = csr_row[j + 7];
        float v0 = bf2f(hp[r0 * 64 + c]);
        float v1 = bf2f(hp[r1 * 64 + c]);
        float v2 = bf2f(hp[r2 * 64 + c]);
        float v3 = bf2f(hp[r3 * 64 + c]);
        float v4 = bf2f(hp[r4 * 64 + c]);
        float v5 = bf2f(hp[r5 * 64 + c]);
        float v6 = bf2f(hp[r6 * 64 + c]);
        float v7 = bf2f(hp[r7 * 64 + c]);
        a += ((v0 + v1) + (v2 + v3)) + ((v4 + v5) + (v6 + v7));
    }
    for (; j < s1; ++j) a += bf2f(hp[csr_row[j] * 64 + c]);
    partial[(size_t)node * 64 + c] = a;
}

// final phase: gather last chunk, then bias+relu+store+pool.
template <bool WRITE, bool COUNT, int POFF>
__global__ void agg_final_kernel(const int* __restrict__ csr_row, const int* __restrict__ start2,
                                 const ushort_t* __restrict__ hp, const float* __restrict__ partial,
                                 const float* __restrict__ dinv, const float* __restrict__ b,
                                 float* __restrict__ out, const int* __restrict__ batch,
                                 float* __restrict__ pooled, float* __restrict__ cntg) {
    int node = blockIdx.x * 4 + (threadIdx.x >> 6);
    int c = threadIdx.x & 63;
    const int ph = N_CHUNKS - 1;
    int s0 = start2[node * N_CHUNKS + ph];
    int s1 = start2[node * N_CHUNKS + ph + 1];
    float a = partial[(size_t)node * 64 + c];
    int j = s0;
    for (; j + 7 < s1; j += 8) {
        int r0 = csr_row[j + 0];
        int r1 = csr_row[j + 1];
        int r2 = csr_row[j + 2];
        int r3 = csr_row[j + 3];
        int r4 = csr_row[j + 4];
        int r5 = csr_row[j + 5];
        int r6 = csr_row[j + 6];
        int r7 = csr_row[j + 7];
        float v0 = bf2f(hp[r0 * 64 + c]);
        float v1 = bf2f(hp[r1 * 64 + c]);
        float v2 = bf2f(hp[r2 * 64 + c]);
        float v3 = bf2f(hp[r3 * 64 + c]);
        float v4 = bf2f(hp[r4 * 64 + c]);
        float v5 = bf2f(hp[r5 * 64 + c]);
        float v6 = bf2f(hp[r6 * 64 + c]);
        float v7 = bf2f(hp[r7 * 64 + c]);
        a += ((v0 + v1) + (v2 + v3)) + ((v4 + v5) + (v6 + v7));
    }
    for (; j < s1; ++j) a += bf2f(hp[csr_row[j] * 64 + c]);
    float v = fmaxf(dinv[node] * a + b[c], 0.0f);
    if (WRITE) out[(size_t)node * 64 + c] = v;
    int g = batch[node];
    atomicAdd(&pooled[g * F_CAT + POFF + c], v);
    if (COUNT && c == 0) atomicAdd(&cntg[g], 1.0f);
}

// ------------------------------------------------------------------ head ----
__global__ void head_kernel(const float* __restrict__ pooled, const float* __restrict__ cnt,
                            const float* __restrict__ Wf, const float* __restrict__ bf,
                            float* __restrict__ out) {
    __shared__ float p[F_CAT];
    __shared__ float logits[F_OUT];
    int g = blockIdx.x;
    int tid = threadIdx.x;  // 64
    float invc = 1.0f / fmaxf(cnt[g], 1.0f);
    for (int i = tid; i < F_CAT; i += 64) p[i] = pooled[g * F_CAT + i] * invc;
    __syncthreads();
    if (tid < F_OUT) {
        float acc = bf[tid];
        for (int k = 0; k < F_CAT; ++k) acc += p[k] * Wf[k * F_OUT + tid];
        logits[tid] = acc;
    }
    __syncthreads();
    if (tid == 0) {
        float m = -1e30f;
        for (int j = 0; j < F_OUT; ++j) m = fmaxf(m, logits[j]);
        float s = 0.0f;
        float ex[F_OUT];
        for (int j = 0; j < F_OUT; ++j) { ex[j] = __expf(logits[j] - m); s += ex[j]; }
        float inv = 1.0f / s;
        for (int j = 0; j < F_OUT; ++j) out[g * F_OUT + j] = ex[j] * inv;
    }
}

// ---------------------------------------------------------------- launch ----
extern "C" void kernel_launch(void* const* d_in, const int* in_sizes, int n_in,
                              void* d_out, int out_size, void* d_ws, size_t ws_size,
                              hipStream_t stream) {
    const float* X0 = (const float*)d_in[0];
    const int* ei = (const int*)d_in[1];
    const int* batch = (const int*)d_in[2];
    const float* W1 = (const float*)d_in[3];
    const float* b1 = (const float*)d_in[4];
    const float* W2 = (const float*)d_in[5];
    const float* b2 = (const float*)d_in[6];
    const float* W3 = (const float*)d_in[7];
    const float* b3 = (const float*)d_in[8];
    const float* Wf = (const float*)d_in[9];
    const float* bf = (const float*)d_in[10];
    float* out = (float*)d_out;

    const int* row = ei;
    const int* col = ei + N_EDGES;

    const int SCAN_BLOCKS = (N_CNT + 1023) / 1024;  // 391

    // ---- workspace layout ----
    char* wp = (char*)d_ws;
    int* cnt2 = (int*)wp;       wp += (size_t)N_CNT * 4;
    int* cursor2 = (int*)wp;    wp += (size_t)N_CNT * 4;
    float* pooled = (float*)wp; wp += (size_t)N_GRAPHS * F_CAT * 4;
    float* cntg = (float*)wp;   wp += (size_t)N_GRAPHS * 4;
    size_t zero_bytes = (size_t)(wp - (char*)d_ws);
    float* dinv = (float*)wp;   wp += (size_t)N_NODES * 4;
    int* start2 = (int*)wp;     wp += (size_t)(N_CNT + 4) * 4;
    int* bsum = (int*)wp;       wp += (size_t)512 * 4;
    int* csr_row = (int*)wp;    wp += (size_t)N_EDGES * 4;
    ushort_t* h = (ushort_t*)wp; wp += (size_t)N_NODES * 64 * 2;
    float* partial = (float*)wp; wp += (size_t)N_NODES * 64 * 4;
    float* x1 = (float*)wp;     wp += (size_t)N_NODES * 64 * 4;
    float* x2 = (float*)wp;     wp += (size_t)N_NODES * 64 * 4;

    hipMemsetAsync(d_ws, 0, zero_bytes, stream);

    deg2_kernel<<<(N_EDGES + 255) / 256, 256, 0, stream>>>(row, col, cnt2);
    dinv_kernel<<<(N_NODES + 255) / 256, 256, 0, stream>>>(cnt2, dinv);
    scan1_kernel<<<SCAN_BLOCKS, 1024, 0, stream>>>(cnt2, start2, bsum);
    scan2_kernel<<<1, 512, 0, stream>>>(bsum, SCAN_BLOCKS);
    scan3_kernel<<<(N_CNT + 255) / 256, 256, 0, stream>>>(start2, bsum);
    place_kernel<<<(N_EDGES + 255) / 256, 256, 0, stream>>>(row, col, start2, cursor2, csr_row);

    const int gemm_blocks = (N_NODES + 15) / 16;
    const int agg_blocks = N_NODES / 4;  // 25000 exact

    // ---- layer 1 ----
    gemm_kernel<128><<<gemm_blocks, 256, 0, stream>>>(X0, W1, dinv, h);
    agg_phase_kernel<<<agg_blocks, 256, 0, stream>>>(csr_row, start2, h, partial, 0, 1);
    agg_phase_kernel<<<agg_blocks, 256, 0, stream>>>(csr_row, start2, h, partial, 1, 0);
    agg_phase_kernel<<<agg_blocks, 256, 0, stream>>>(csr_row, start2, h, partial, 2, 0);
    agg_final_kernel<true, true, 0><<<agg_blocks, 256, 0, stream>>>(
        csr_row, start2, h, partial, dinv, b1, x1, batch, pooled, cntg);
    // ---- layer 2 ----
    gemm_kernel<64><<<gemm_blocks, 256, 0, stream>>>(x1, W2, dinv, h);
    agg_phase_kernel<<<agg_blocks, 256, 0, stream>>>(csr_row, start2, h, partial, 0, 1);
    agg_phase_kernel<<<agg_blocks, 256, 0, stream>>>(csr_row, start2, h, partial, 1, 0);
    agg_phase_kernel<<<agg_blocks, 256, 0, stream>>>(csr_row, start2, h, partial, 2, 0);
    agg_final_kernel<true, false, 64><<<agg_blocks, 256, 0, stream>>>(
        csr_row, start2, h, partial, dinv, b2, x2, batch, pooled, cntg);
    // ---- layer 3 ----
    gemm_kernel<64><<<gemm_blocks, 256, 0, stream>>>(x2, W3, dinv, h);
    agg_phase_kernel<<<agg_blocks, 256, 0, stream>>>(csr_row, start2, h, partial, 0, 1);
    agg_phase_kernel<<<agg_blocks, 256, 0, stream>>>(csr_row, start2, h, partial, 1, 0);
    agg_phase_kernel<<<agg_blocks, 256, 0, stream>>>(csr_row, start2, h, partial, 2, 0);
    agg_final_kernel<false, false, 128><<<agg_blocks, 256, 0, stream>>>(
        csr_row, start2, h, partial, dinv, b3, nullptr, batch, pooled, cntg);
    // ---- head ----
    head_kernel<<<N_GRAPHS, 64, 0, stream>>>(pooled, cntg, Wf, bf, out);
}

// Round 10
// 1193.892 us; speedup vs baseline: 1.8041x; 1.1721x over previous
//
#include <hip/hip_runtime.h>

#define N_NODES 100000
#define N_EDGES 3200000
#define N_GRAPHS 512
#define F_IN 128
#define F_HID 64
#define F_CAT 192
#define F_OUT 10

#define N_CHUNKS 4
#define CHUNK_DIV 25000             // nodes per source-chunk; hp slice = 3.2 MB < 4 MB XCD L2
#define N_CNT (N_NODES * N_CHUNKS)  // 400000 counters

typedef unsigned short ushort_t;
typedef unsigned int uint_t;

static __device__ __forceinline__ ushort_t f2bf(float f) {
    uint_t u = __float_as_uint(f);
    u = (u + 0x7FFFu + ((u >> 16) & 1u)) >> 16;  // round-to-nearest-even
    return (ushort_t)u;
}
static __device__ __forceinline__ float bf2f(ushort_t h) {
    return __uint_as_float((uint_t)h << 16);
}

// ------------------------------------------- per-(dest,src-chunk) histogram ----
__global__ void deg2_kernel(const int* __restrict__ row, const int* __restrict__ col,
                            int* __restrict__ cnt2) {
    int e = blockIdx.x * blockDim.x + threadIdx.x;
    if (e < N_EDGES) {
        int ch = row[e] / CHUNK_DIV;
        atomicAdd(&cnt2[col[e] * N_CHUNKS + ch], 1);
    }
}

__global__ void dinv_kernel(const int* __restrict__ cnt2, float* __restrict__ dinv) {
    int i = blockIdx.x * blockDim.x + threadIdx.x;
    if (i < N_NODES) {
        int d = cnt2[i * 4] + cnt2[i * 4 + 1] + cnt2[i * 4 + 2] + cnt2[i * 4 + 3];
        dinv[i] = d > 0 ? rsqrtf((float)d) : 0.0f;
    }
}

// ------------------------------------------------- two-level prefix scan ----
__global__ void scan1_kernel(const int* __restrict__ cnt, int* __restrict__ start,
                             int* __restrict__ bsum) {
    __shared__ int s[1024];
    int t = threadIdx.x;  // 1024
    int i = blockIdx.x * 1024 + t;
    int v = (i < N_CNT) ? cnt[i] : 0;
    s[t] = v;
    __syncthreads();
    for (int o = 1; o < 1024; o <<= 1) {
        int x = (t >= o) ? s[t - o] : 0;
        __syncthreads();
        s[t] += x;
        __syncthreads();
    }
    if (i < N_CNT) start[i] = s[t] - v;
    if (t == 1023) bsum[blockIdx.x] = s[1023];
}

__global__ void scan2_kernel(int* __restrict__ bsum, int nblk) {
    __shared__ int s[512];
    int t = threadIdx.x;  // 512
    int v = (t < nblk) ? bsum[t] : 0;
    s[t] = v;
    __syncthreads();
    for (int o = 1; o < 512; o <<= 1) {
        int x = (t >= o) ? s[t - o] : 0;
        __syncthreads();
        s[t] += x;
        __syncthreads();
    }
    if (t < nblk) bsum[t] = s[t] - v;
}

__global__ void scan3_kernel(int* __restrict__ start, const int* __restrict__ bsum) {
    int i = blockIdx.x * blockDim.x + threadIdx.x;
    if (i < N_CNT) start[i] += bsum[i >> 10];
    if (i == 0) start[N_CNT] = N_EDGES;
}

// ------------------------------------------------------- CSC placement -----
__global__ void place_kernel(const int* __restrict__ row, const int* __restrict__ col,
                             const int* __restrict__ start2, int* __restrict__ cursor2,
                             int* __restrict__ csr_row) {
    int e = blockIdx.x * blockDim.x + threadIdx.x;
    if (e < N_EDGES) {
        int r = row[e];
        int d = col[e];
        int slot = d * N_CHUNKS + r / CHUNK_DIV;
        int ofs = atomicAdd(&cursor2[slot], 1);
        csr_row[start2[slot] + ofs] = r;
    }
}

// -------------------------------------------------- graph range boundaries ----
// batch is sorted; gstart[g] = first node of graph g; gstart[N_GRAPHS] = N.
__global__ void gbound_kernel(const int* __restrict__ batch, int* __restrict__ gstart) {
    int i = blockIdx.x * blockDim.x + threadIdx.x;
    if (i < N_NODES) {
        int b = batch[i];
        int bp = (i == 0) ? -1 : batch[i - 1];
        for (int g = bp + 1; g <= b; ++g) gstart[g] = i;
        if (i == N_NODES - 1)
            for (int g = b + 1; g <= N_GRAPHS; ++g) gstart[g] = N_NODES;
    }
}

// ------------------------------------------------------------------ GEMM ----
template <int K>
__global__ void gemm_kernel(const float* __restrict__ X, const float* __restrict__ W,
                            const float* __restrict__ dinv, ushort_t* __restrict__ HP) {
    __shared__ float Ws[K][64];
    __shared__ float Xs[16][K];
    int tid = threadIdx.x;  // 256
    for (int i = tid; i < K * 64; i += 256) Ws[i / 64][i % 64] = W[i];
    int row0 = blockIdx.x * 16;
    for (int i = tid; i < 16 * K; i += 256) {
        int r = i / K, k = i % K;
        int gr = row0 + r;
        Xs[r][k] = (gr < N_NODES) ? X[(size_t)gr * K + k] : 0.0f;
    }
    __syncthreads();
    int c = tid & 63;
    int rs = tid >> 6;
    for (int r = rs; r < 16; r += 4) {
        float acc = 0.0f;
#pragma unroll
        for (int k = 0; k < K; ++k) acc += Xs[r][k] * Ws[k][c];
        int gr = row0 + r;
        if (gr < N_NODES) HP[(size_t)gr * 64 + c] = f2bf(acc * dinv[gr]);
    }
}

// -------------------------------------------------------- phased aggregate ----
// Per phase ph: one wave per node, gather only from hp slice ph (3.2 MB,
// L2-resident). partial[node][c] accumulates across the 4 phase dispatches.
__global__ void agg_phase_kernel(const int* __restrict__ csr_row, const int* __restrict__ start2,
                                 const ushort_t* __restrict__ hp, float* __restrict__ partial,
                                 int ph, int first) {
    int node = blockIdx.x * 4 + (threadIdx.x >> 6);  // exact: 100000 = 4*25000
    int c = threadIdx.x & 63;
    int s0 = start2[node * N_CHUNKS + ph];
    int s1 = start2[node * N_CHUNKS + ph + 1];
    float a = first ? 0.0f : partial[(size_t)node * 64 + c];
    int j = s0;
    for (; j + 7 < s1; j += 8) {
        int r0 = csr_row[j + 0];
        int r1 = csr_row[j + 1];
        int r2 = csr_row[j + 2];
        int r3 = csr_row[j + 3];
        int r4 = csr_row[j + 4];
        int r5 = csr_row[j + 5];
        int r6 = csr_row[j + 6];
        int r7 = csr_row[j + 7];
        float v0 = bf2f(hp[r0 * 64 + c]);
        float v1 = bf2f(hp[r1 * 64 + c]);
        float v2 = bf2f(hp[r2 * 64 + c]);
        float v3 = bf2f(hp[r3 * 64 + c]);
        float v4 = bf2f(hp[r4 * 64 + c]);
        float v5 = bf2f(hp[r5 * 64 + c]);
        float v6 = bf2f(hp[r6 * 64 + c]);
        float v7 = bf2f(hp[r7 * 64 + c]);
        a += ((v0 + v1) + (v2 + v3)) + ((v4 + v5) + (v6 + v7));
    }
    for (; j < s1; ++j) a += bf2f(hp[csr_row[j] * 64 + c]);
    partial[(size_t)node * 64 + c] = a;
}

// final phase: gather last chunk, bias+relu, store. NO atomics.
// outp may alias partial (layer 3): same-thread read-then-write is safe.
__global__ void agg_final_kernel(const int* __restrict__ csr_row, const int* __restrict__ start2,
                                 const ushort_t* __restrict__ hp, float* __restrict__ partial,
                                 const float* __restrict__ dinv, const float* __restrict__ b,
                                 float* __restrict__ outp) {
    int node = blockIdx.x * 4 + (threadIdx.x >> 6);
    int c = threadIdx.x & 63;
    const int ph = N_CHUNKS - 1;
    int s0 = start2[node * N_CHUNKS + ph];
    int s1 = start2[node * N_CHUNKS + ph + 1];
    float a = partial[(size_t)node * 64 + c];
    int j = s0;
    for (; j + 7 < s1; j += 8) {
        int r0 = csr_row[j + 0];
        int r1 = csr_row[j + 1];
        int r2 = csr_row[j + 2];
        int r3 = csr_row[j + 3];
        int r4 = csr_row[j + 4];
        int r5 = csr_row[j + 5];
        int r6 = csr_row[j + 6];
        int r7 = csr_row[j + 7];
        float v0 = bf2f(hp[r0 * 64 + c]);
        float v1 = bf2f(hp[r1 * 64 + c]);
        float v2 = bf2f(hp[r2 * 64 + c]);
        float v3 = bf2f(hp[r3 * 64 + c]);
        float v4 = bf2f(hp[r4 * 64 + c]);
        float v5 = bf2f(hp[r5 * 64 + c]);
        float v6 = bf2f(hp[r6 * 64 + c]);
        float v7 = bf2f(hp[r7 * 64 + c]);
        a += ((v0 + v1) + (v2 + v3)) + ((v4 + v5) + (v6 + v7));
    }
    for (; j < s1; ++j) a += bf2f(hp[csr_row[j] * 64 + c]);
    float v = fmaxf(dinv[node] * a + b[c], 0.0f);
    outp[(size_t)node * 64 + c] = v;
}

// ------------------------------------------------------------------ pool ----
// One block per graph (contiguous node range), 192 threads = channels.
// Plain coalesced reads, no atomics; writes mean-pooled features.
__global__ void pool_kernel(const float* __restrict__ x1, const float* __restrict__ x2,
                            const float* __restrict__ x3, const int* __restrict__ gstart,
                            float* __restrict__ pooled) {
    int g = blockIdx.x;
    int c = threadIdx.x;  // 192
    int r0 = gstart[g], r1 = gstart[g + 1];
    const float* src = (c < 64) ? x1 : ((c < 128) ? x2 : x3);
    int cc = c & 63;
    float a0 = 0, a1 = 0, a2 = 0, a3 = 0;
    int i = r0;
    for (; i + 3 < r1; i += 4) {
        a0 += src[(size_t)(i + 0) * 64 + cc];
        a1 += src[(size_t)(i + 1) * 64 + cc];
        a2 += src[(size_t)(i + 2) * 64 + cc];
        a3 += src[(size_t)(i + 3) * 64 + cc];
    }
    for (; i < r1; ++i) a0 += src[(size_t)i * 64 + cc];
    float s = (a0 + a1) + (a2 + a3);
    int cnt = r1 - r0;
    pooled[g * F_CAT + c] = s / (float)(cnt > 0 ? cnt : 1);
}

// ------------------------------------------------------------------ head ----
__global__ void head_kernel(const float* __restrict__ pooled, const float* __restrict__ Wf,
                            const float* __restrict__ bf, float* __restrict__ out) {
    __shared__ float p[F_CAT];
    __shared__ float logits[F_OUT];
    int g = blockIdx.x;
    int tid = threadIdx.x;  // 64
    for (int i = tid; i < F_CAT; i += 64) p[i] = pooled[g * F_CAT + i];
    __syncthreads();
    if (tid < F_OUT) {
        float acc = bf[tid];
        for (int k = 0; k < F_CAT; ++k) acc += p[k] * Wf[k * F_OUT + tid];
        logits[tid] = acc;
    }
    __syncthreads();
    if (tid == 0) {
        float m = -1e30f;
        for (int j = 0; j < F_OUT; ++j) m = fmaxf(m, logits[j]);
        float s = 0.0f;
        float ex[F_OUT];
        for (int j = 0; j < F_OUT; ++j) { ex[j] = __expf(logits[j] - m); s += ex[j]; }
        float inv = 1.0f / s;
        for (int j = 0; j < F_OUT; ++j) out[g * F_OUT + j] = ex[j] * inv;
    }
}

// ---------------------------------------------------------------- launch ----
extern "C" void kernel_launch(void* const* d_in, const int* in_sizes, int n_in,
                              void* d_out, int out_size, void* d_ws, size_t ws_size,
                              hipStream_t stream) {
    const float* X0 = (const float*)d_in[0];
    const int* ei = (const int*)d_in[1];
    const int* batch = (const int*)d_in[2];
    const float* W1 = (const float*)d_in[3];
    const float* b1 = (const float*)d_in[4];
    const float* W2 = (const float*)d_in[5];
    const float* b2 = (const float*)d_in[6];
    const float* W3 = (const float*)d_in[7];
    const float* b3 = (const float*)d_in[8];
    const float* Wf = (const float*)d_in[9];
    const float* bf = (const float*)d_in[10];
    float* out = (float*)d_out;

    const int* row = ei;
    const int* col = ei + N_EDGES;

    const int SCAN_BLOCKS = (N_CNT + 1023) / 1024;  // 391

    // ---- workspace layout ----
    char* wp = (char*)d_ws;
    int* cnt2 = (int*)wp;       wp += (size_t)N_CNT * 4;
    int* cursor2 = (int*)wp;    wp += (size_t)N_CNT * 4;
    size_t zero_bytes = (size_t)(wp - (char*)d_ws);
    float* pooled = (float*)wp; wp += (size_t)N_GRAPHS * F_CAT * 4;
    int* gstart = (int*)wp;     wp += (size_t)(N_GRAPHS + 4) * 4;
    float* dinv = (float*)wp;   wp += (size_t)N_NODES * 4;
    int* start2 = (int*)wp;     wp += (size_t)(N_CNT + 4) * 4;
    int* bsum = (int*)wp;       wp += (size_t)512 * 4;
    int* csr_row = (int*)wp;    wp += (size_t)N_EDGES * 4;
    ushort_t* h = (ushort_t*)wp; wp += (size_t)N_NODES * 64 * 2;
    float* partial = (float*)wp; wp += (size_t)N_NODES * 64 * 4;
    float* x1 = (float*)wp;     wp += (size_t)N_NODES * 64 * 4;
    float* x2 = (float*)wp;     wp += (size_t)N_NODES * 64 * 4;

    hipMemsetAsync(d_ws, 0, zero_bytes, stream);

    deg2_kernel<<<(N_EDGES + 255) / 256, 256, 0, stream>>>(row, col, cnt2);
    dinv_kernel<<<(N_NODES + 255) / 256, 256, 0, stream>>>(cnt2, dinv);
    scan1_kernel<<<SCAN_BLOCKS, 1024, 0, stream>>>(cnt2, start2, bsum);
    scan2_kernel<<<1, 512, 0, stream>>>(bsum, SCAN_BLOCKS);
    scan3_kernel<<<(N_CNT + 255) / 256, 256, 0, stream>>>(start2, bsum);
    place_kernel<<<(N_EDGES + 255) / 256, 256, 0, stream>>>(row, col, start2, cursor2, csr_row);
    gbound_kernel<<<(N_NODES + 255) / 256, 256, 0, stream>>>(batch, gstart);

    const int gemm_blocks = (N_NODES + 15) / 16;
    const int agg_blocks = N_NODES / 4;  // 25000 exact

    // ---- layer 1 ----
    gemm_kernel<128><<<gemm_blocks, 256, 0, stream>>>(X0, W1, dinv, h);
    agg_phase_kernel<<<agg_blocks, 256, 0, stream>>>(csr_row, start2, h, partial, 0, 1);
    agg_phase_kernel<<<agg_blocks, 256, 0, stream>>>(csr_row, start2, h, partial, 1, 0);
    agg_phase_kernel<<<agg_blocks, 256, 0, stream>>>(csr_row, start2, h, partial, 2, 0);
    agg_final_kernel<<<agg_blocks, 256, 0, stream>>>(csr_row, start2, h, partial, dinv, b1, x1);
    // ---- layer 2 ----
    gemm_kernel<64><<<gemm_blocks, 256, 0, stream>>>(x1, W2, dinv, h);
    agg_phase_kernel<<<agg_blocks, 256, 0, stream>>>(csr_row, start2, h, partial, 0, 1);
    agg_phase_kernel<<<agg_blocks, 256, 0, stream>>>(csr_row, start2, h, partial, 1, 0);
    agg_phase_kernel<<<agg_blocks, 256, 0, stream>>>(csr_row, start2, h, partial, 2, 0);
    agg_final_kernel<<<agg_blocks, 256, 0, stream>>>(csr_row, start2, h, partial, dinv, b2, x2);
    // ---- layer 3 ----
    gemm_kernel<64><<<gemm_blocks, 256, 0, stream>>>(x2, W3, dinv, h);
    agg_phase_kernel<<<agg_blocks, 256, 0, stream>>>(csr_row, start2, h, partial, 0, 1);
    agg_phase_kernel<<<agg_blocks, 256, 0, stream>>>(csr_row, start2, h, partial, 1, 0);
    agg_phase_kernel<<<agg_blocks, 256, 0, stream>>>(csr_row, start2, h, partial, 2, 0);
    agg_final_kernel<<<agg_blocks, 256, 0, stream>>>(csr_row, start2, h, partial, dinv, b3,
                                                     partial);  // x3 in-place
    // ---- pool + head ----
    pool_kernel<<<N_GRAPHS, 192, 0, stream>>>(x1, x2, partial, gstart, pooled);
    head_kernel<<<N_GRAPHS, 64, 0, stream>>>(pooled, Wf, bf, out);
}